// Round 5
// baseline (123.166 us; speedup 1.0000x reference)
//
#include <hip/hip_runtime.h>

#define MARGIN 0.2f
#define EPS_    1e-8f

typedef _Float16 h2 __attribute__((ext_vector_type(2)));

// ---------------------------------------------------------------------------
// fp32 -> packed fp16 (2 per uint). 8 floats per thread.
// ---------------------------------------------------------------------------
__device__ __forceinline__ unsigned pack_f16(float lo, float hi)
{
#if __has_builtin(__builtin_amdgcn_cvt_pkrtz)
    return __builtin_bit_cast(unsigned, __builtin_amdgcn_cvt_pkrtz(lo, hi));
#else
    h2 p; p[0] = (_Float16)lo; p[1] = (_Float16)hi;
    return __builtin_bit_cast(unsigned, p);
#endif
}

__global__ __launch_bounds__(256) void to_f16_kernel(
    const float* __restrict__ in, uint4* __restrict__ out, int n8)
{
    int i = blockIdx.x * blockDim.x + threadIdx.x;
    if (i >= n8) return;
    const float4 a = ((const float4*)in)[2 * i + 0];
    const float4 b = ((const float4*)in)[2 * i + 1];
    uint4 r;
    r.x = pack_f16(a.x, a.y);
    r.y = pack_f16(a.z, a.w);
    r.z = pack_f16(b.x, b.y);
    r.w = pack_f16(b.z, b.w);
    out[i] = r;
}

__global__ void beta_row_kernel(const float* __restrict__ beta,
                                const int*   __restrict__ labels,
                                float*       __restrict__ beta_row, int B)
{
    int i = blockIdx.x * blockDim.x + threadIdx.x;
    if (i < B) beta_row[i] = beta[labels[i]];
}

// ---------------------------------------------------------------------------
// Hot kernel, D == 512, fp16 rows (1 KB = 64 uint4 per row).
// One triplet per 16-lane quarter; 4 triplets per wave; ONE batch per wave
// (no loop -> nothing to sink). Each lane issues 12 independent dwordx4
// loads (4 A, 4 P, 4 N) before any compute.
// ---------------------------------------------------------------------------
__device__ __forceinline__ void accd(unsigned ua, unsigned uq, float& s)
{
    h2 a = __builtin_bit_cast(h2, ua);
    h2 q = __builtin_bit_cast(h2, uq);
    h2 d = a - q;                       // packed f16 sub
#if __has_builtin(__builtin_amdgcn_fdot2)
    s = __builtin_amdgcn_fdot2(d, d, s, false);   // s += d0*d0 + d1*d1
#else
    const float d0 = (float)d[0], d1 = (float)d[1];
    s = fmaf(d0, d0, s);
    s = fmaf(d1, d1, s);
#endif
}

__global__ __launch_bounds__(256) void triplet_loss_f16_d512(
    const uint4* __restrict__ hb,
    const float* __restrict__ brow,
    const int*   __restrict__ triplets,
    int T,
    float*        __restrict__ ws_total,
    unsigned int* __restrict__ ws_cnt)
{
    const int lane = threadIdx.x & 63;
    const int wid  = threadIdx.x >> 6;
    const int q    = lane >> 4;          // quarter 0..3
    const int l16  = lane & 15;

    const int t     = blockIdx.x * 16 + wid * 4 + q;
    const bool valid = t < T;
    const int tt    = valid ? t : 0;

    const int t0 = triplets[3 * tt + 0];
    const int t1 = triplets[3 * tt + 1];
    const int t2 = triplets[3 * tt + 2];

    const uint4* A = hb + (size_t)t0 * 64;
    const uint4* P = hb + (size_t)t1 * 64;
    const uint4* N = hb + (size_t)t2 * 64;

    // issue all 12 loads up front (independent -> all in flight)
    uint4 va[4], vp[4], vn[4];
    #pragma unroll
    for (int k = 0; k < 4; ++k) va[k] = A[l16 + 16 * k];
    #pragma unroll
    for (int k = 0; k < 4; ++k) vp[k] = P[l16 + 16 * k];
    #pragma unroll
    for (int k = 0; k < 4; ++k) vn[k] = N[l16 + 16 * k];
    const float b = brow[t0];

    float sap = 0.0f, san = 0.0f;
    #pragma unroll
    for (int k = 0; k < 4; ++k) {
        accd(va[k].x, vp[k].x, sap);
        accd(va[k].y, vp[k].y, sap);
        accd(va[k].z, vp[k].z, sap);
        accd(va[k].w, vp[k].w, sap);
        accd(va[k].x, vn[k].x, san);
        accd(va[k].y, vn[k].y, san);
        accd(va[k].z, vn[k].z, san);
        accd(va[k].w, vn[k].w, san);
    }

    // 4-step butterfly within each 16-lane quarter (DPP-cheap offsets)
    #pragma unroll
    for (int off = 1; off < 16; off <<= 1) {
        sap += __shfl_xor(sap, off, 64);
        san += __shfl_xor(san, off, 64);
    }

    float        tot = 0.0f;
    unsigned int cnt = 0u;
    if (l16 == 0 && valid) {
        const float d_ap = sqrtf(sap + EPS_);
        const float d_an = sqrtf(san + EPS_);
        const float pos  = fmaxf(d_ap - b + MARGIN, 0.0f);
        const float neg  = fmaxf(b - d_an + MARGIN, 0.0f);
        tot = pos + neg;
        cnt = ((pos > 0.0f) || (neg > 0.0f)) ? 1u : 0u;
    }

    __shared__ float        s_tot[16];
    __shared__ unsigned int s_cnt[16];
    if (l16 == 0) { s_tot[wid * 4 + q] = tot; s_cnt[wid * 4 + q] = cnt; }
    __syncthreads();
    if (threadIdx.x == 0) {
        float        bt = 0.0f;
        unsigned int bc = 0u;
        #pragma unroll
        for (int i = 0; i < 16; ++i) { bt += s_tot[i]; bc += s_cnt[i]; }
        atomicAdd(ws_total, bt);
        atomicAdd(ws_cnt, bc);
    }
}

// ---------------------------------------------------------------------------
// Standalone fp32 fallback (any D % 4 == 0; needs only 8 B of ws).
// ---------------------------------------------------------------------------
__global__ __launch_bounds__(256) void triplet_loss_generic(
    const float* __restrict__ batch,
    const float* __restrict__ beta,
    const int*   __restrict__ labels,
    const int*   __restrict__ triplets,
    int T, int D,
    float*        __restrict__ ws_total,
    unsigned int* __restrict__ ws_cnt)
{
    const int lane   = threadIdx.x & 63;
    const int wid    = threadIdx.x >> 6;
    const int gwave  = (blockIdx.x * blockDim.x + threadIdx.x) >> 6;
    const int nwaves = (gridDim.x * blockDim.x) >> 6;
    const int dq     = D >> 2;

    float        tot = 0.0f;
    unsigned int cnt = 0u;

    for (int t = gwave; t < T; t += nwaves) {
        const int t0 = triplets[3 * t + 0];
        const int t1 = triplets[3 * t + 1];
        const int t2 = triplets[3 * t + 2];
        const float4* A = (const float4*)(batch + (size_t)t0 * D);
        const float4* P = (const float4*)(batch + (size_t)t1 * D);
        const float4* N = (const float4*)(batch + (size_t)t2 * D);
        float sap = 0.0f, san = 0.0f;
        for (int idx = lane; idx < dq; idx += 64) {
            const float4 av = A[idx];
            const float4 pv = P[idx];
            const float4 nv = N[idx];
            float dx = av.x - pv.x, dy = av.y - pv.y, dz = av.z - pv.z, dw = av.w - pv.w;
            sap += dx * dx + dy * dy + dz * dz + dw * dw;
            dx = av.x - nv.x; dy = av.y - nv.y; dz = av.z - nv.z; dw = av.w - nv.w;
            san += dx * dx + dy * dy + dz * dz + dw * dw;
        }
        #pragma unroll
        for (int off = 1; off < 64; off <<= 1) {
            sap += __shfl_xor(sap, off, 64);
            san += __shfl_xor(san, off, 64);
        }
        if (lane == 0) {
            const float d_ap = sqrtf(sap + EPS_);
            const float d_an = sqrtf(san + EPS_);
            const float b    = beta[labels[t0]];
            const float pos  = fmaxf(d_ap - b + MARGIN, 0.0f);
            const float neg  = fmaxf(b - d_an + MARGIN, 0.0f);
            tot += pos + neg;
            cnt += ((pos > 0.0f) || (neg > 0.0f)) ? 1u : 0u;
        }
    }

    __shared__ float        s_tot[4];
    __shared__ unsigned int s_cnt[4];
    if (lane == 0) { s_tot[wid] = tot; s_cnt[wid] = cnt; }
    __syncthreads();
    if (threadIdx.x == 0) {
        float        bt = 0.0f;
        unsigned int bc = 0u;
        const int nw = blockDim.x >> 6;
        for (int i = 0; i < nw; ++i) { bt += s_tot[i]; bc += s_cnt[i]; }
        atomicAdd(ws_total, bt);
        atomicAdd(ws_cnt, bc);
    }
}

__global__ void finalize_kernel(const float* __restrict__ ws_total,
                                const unsigned int* __restrict__ ws_cnt,
                                float* __restrict__ out)
{
    const float total = ws_total[0];
    const float pc    = (float)ws_cnt[0];
    out[0] = (pc > 0.0f) ? (total / fmaxf(pc, 1.0f)) : total;
}

extern "C" void kernel_launch(void* const* d_in, const int* in_sizes, int n_in,
                              void* d_out, int out_size, void* d_ws, size_t ws_size,
                              hipStream_t stream)
{
    const float* batch    = (const float*)d_in[0];
    const float* beta     = (const float*)d_in[1];
    const int*   labels   = (const int*)d_in[2];
    const int*   triplets = (const int*)d_in[3];

    const int B = in_sizes[2];            // 4096
    const int D = in_sizes[0] / B;        // 512
    const int T = in_sizes[3] / 3;        // 65536

    float*        ws_total = (float*)d_ws;
    unsigned int* ws_cnt   = (unsigned int*)((char*)d_ws + sizeof(float));

    // zero accumulators every call (harness does not re-poison between replays)
    (void)hipMemsetAsync(d_ws, 0, 2 * sizeof(float), stream);

    // ws layout: [0,8) accumulators | [1024,+4B) beta_row | [32768,+4MiB) f16 batch
    const size_t brow_off = 1024;
    const size_t hb_off   = 32768;
    const size_t need     = hb_off + (size_t)B * D * 2;
    const bool fast = (D == 512) && (ws_size >= need);

    if (fast) {
        float* beta_row = (float*)((char*)d_ws + brow_off);
        uint4* hb       = (uint4*)((char*)d_ws + hb_off);

        const int n8 = (B * D) / 8;
        to_f16_kernel<<<(n8 + 255) / 256, 256, 0, stream>>>(batch, hb, n8);
        beta_row_kernel<<<(B + 255) / 256, 256, 0, stream>>>(beta, labels, beta_row, B);

        const int grid = (T + 15) / 16;   // 16 triplets per 256-thread block
        triplet_loss_f16_d512<<<grid, 256, 0, stream>>>(
            hb, beta_row, triplets, T, ws_total, ws_cnt);
    } else {
        const int block = 256;
        int grid = 2048;
        const int max_grid = (T + 3) / 4;
        if (grid > max_grid) grid = max_grid;
        triplet_loss_generic<<<grid, block, 0, stream>>>(
            batch, beta, labels, triplets, T, D, ws_total, ws_cnt);
    }

    finalize_kernel<<<1, 1, 0, stream>>>(ws_total, ws_cnt, (float*)d_out);
}

// Round 6
// 78.014 us; speedup vs baseline: 1.5788x; 1.5788x over previous
//
#include <hip/hip_runtime.h>

#define MARGIN 0.2f
#define EPS_    1e-8f

// ---------------------------------------------------------------------------
// fp32 -> bf16 (RNE), packed 2/uint. 8 floats per thread.
// ---------------------------------------------------------------------------
__device__ __forceinline__ unsigned pack_bf16(float lo, float hi)
{
    union { float f; unsigned u; } a, b;
    a.f = lo; b.f = hi;
    unsigned ua = (a.u + 0x7fffu + ((a.u >> 16) & 1u)) >> 16;
    unsigned ub = (b.u + 0x7fffu + ((b.u >> 16) & 1u)) & 0xffff0000u;
    return ua | ub;
}

__global__ __launch_bounds__(256) void to_bf16_kernel(
    const float* __restrict__ in, uint4* __restrict__ out, int n8)
{
    int i = blockIdx.x * blockDim.x + threadIdx.x;
    if (i >= n8) return;
    const float4 a = ((const float4*)in)[2 * i + 0];
    const float4 b = ((const float4*)in)[2 * i + 1];
    uint4 r;
    r.x = pack_bf16(a.x, a.y);
    r.y = pack_bf16(a.z, a.w);
    r.z = pack_bf16(b.x, b.y);
    r.w = pack_bf16(b.z, b.w);
    out[i] = r;
}

__global__ void beta_row_kernel(const float* __restrict__ beta,
                                const int*   __restrict__ labels,
                                float*       __restrict__ beta_row, int B)
{
    int i = blockIdx.x * blockDim.x + threadIdx.x;
    if (i < B) beta_row[i] = beta[labels[i]];
}

__device__ __forceinline__ void acc2(unsigned ua, unsigned uq, float& s)
{
    union { unsigned x; float f; } al, ah, ql, qh;
    al.x = ua << 16;        ah.x = ua & 0xffff0000u;
    ql.x = uq << 16;        qh.x = uq & 0xffff0000u;
    const float d0 = al.f - ql.f;
    const float d1 = ah.f - qh.f;
    s = fmaf(d0, d0, s);
    s = fmaf(d1, d1, s);
}

// ---------------------------------------------------------------------------
// Hot kernel v2, D == 512, bf16 rows (1 KB = 64 uint4).
// Half-wave split (lanes 0-31: |a-p|^2, lanes 32-63: |a-n|^2).
// Per wave: 2 iterations x 4 triplets. Each iteration issues ALL 16 row-load
// instructions, then sched_barrier(0) pins them (compiler cannot sink), then
// consumes. 16 staged uint4 = 64 VGPRs live across the barrier by construction.
// ---------------------------------------------------------------------------
__global__ __launch_bounds__(256, 4) void triplet_loss_bf16_v2(
    const uint4* __restrict__ hb,
    const float* __restrict__ brow,
    const int*   __restrict__ trip,
    int T,
    float*        __restrict__ ws_total,
    unsigned int* __restrict__ ws_cnt)
{
    const int lane  = threadIdx.x & 63;
    const int wid   = threadIdx.x >> 6;
    const int l32   = lane & 31;
    const int half  = lane >> 5;
    const int gwave = blockIdx.x * 4 + wid;

    float        tot = 0.0f;
    unsigned int cnt = 0u;

    #pragma unroll
    for (int it = 0; it < 2; ++it) {
        const int tb = gwave * 8 + it * 4;

        const uint4* Ap[4];
        const uint4* Qp[4];
        float bv[4];
        bool  val[4];
        #pragma unroll
        for (int u = 0; u < 4; ++u) {
            int t = tb + u;
            val[u] = (t < T);
            t = val[u] ? t : 0;
            int t0 = __builtin_amdgcn_readfirstlane(trip[3 * t + 0]);
            int t1 = __builtin_amdgcn_readfirstlane(trip[3 * t + 1]);
            int t2 = __builtin_amdgcn_readfirstlane(trip[3 * t + 2]);
            Ap[u] = hb + (size_t)t0 * 64;
            Qp[u] = hb + (size_t)(half ? t2 : t1) * 64;
            bv[u] = brow[t0];
        }

        // issue all 16 row loads (4 triplets x {2 A, 2 Q})
        uint4 A[4][2], Q[4][2];
        #pragma unroll
        for (int u = 0; u < 4; ++u) {
            A[u][0] = Ap[u][l32];
            A[u][1] = Ap[u][l32 + 32];
            Q[u][0] = Qp[u][l32];
            Q[u][1] = Qp[u][l32 + 32];
        }
        // pin: nothing above may move below, nothing below may move above
        __builtin_amdgcn_sched_barrier(0);

        #pragma unroll
        for (int u = 0; u < 4; ++u) {
            float s = 0.0f;
            acc2(A[u][0].x, Q[u][0].x, s);
            acc2(A[u][0].y, Q[u][0].y, s);
            acc2(A[u][0].z, Q[u][0].z, s);
            acc2(A[u][0].w, Q[u][0].w, s);
            acc2(A[u][1].x, Q[u][1].x, s);
            acc2(A[u][1].y, Q[u][1].y, s);
            acc2(A[u][1].z, Q[u][1].z, s);
            acc2(A[u][1].w, Q[u][1].w, s);
            #pragma unroll
            for (int off = 1; off < 32; off <<= 1)
                s += __shfl_xor(s, off, 64);
            const float o = __shfl_xor(s, 32, 64);
            if (lane == 0 && val[u]) {
                const float d_ap = sqrtf(s + EPS_);   // lane0 is in the a-p half
                const float d_an = sqrtf(o + EPS_);
                const float b    = bv[u];
                const float pos  = fmaxf(d_ap - b + MARGIN, 0.0f);
                const float neg  = fmaxf(b - d_an + MARGIN, 0.0f);
                tot += pos + neg;
                cnt += ((pos > 0.0f) || (neg > 0.0f)) ? 1u : 0u;
            }
        }
    }

    __shared__ float        s_tot[4];
    __shared__ unsigned int s_cnt[4];
    if (lane == 0) { s_tot[wid] = tot; s_cnt[wid] = cnt; }
    __syncthreads();
    if (threadIdx.x == 0) {
        float        bt = 0.0f;
        unsigned int bc = 0u;
        #pragma unroll
        for (int i = 0; i < 4; ++i) { bt += s_tot[i]; bc += s_cnt[i]; }
        atomicAdd(ws_total, bt);
        atomicAdd(ws_cnt, bc);
    }
}

// ---------------------------------------------------------------------------
// Standalone fp32 fallback (any D % 4 == 0; needs only 8 B of ws).
// ---------------------------------------------------------------------------
__global__ __launch_bounds__(256) void triplet_loss_generic(
    const float* __restrict__ batch,
    const float* __restrict__ beta,
    const int*   __restrict__ labels,
    const int*   __restrict__ triplets,
    int T, int D,
    float*        __restrict__ ws_total,
    unsigned int* __restrict__ ws_cnt)
{
    const int lane   = threadIdx.x & 63;
    const int wid    = threadIdx.x >> 6;
    const int gwave  = (blockIdx.x * blockDim.x + threadIdx.x) >> 6;
    const int nwaves = (gridDim.x * blockDim.x) >> 6;
    const int dq     = D >> 2;

    float        tot = 0.0f;
    unsigned int cnt = 0u;

    for (int t = gwave; t < T; t += nwaves) {
        const int t0 = triplets[3 * t + 0];
        const int t1 = triplets[3 * t + 1];
        const int t2 = triplets[3 * t + 2];
        const float4* A = (const float4*)(batch + (size_t)t0 * D);
        const float4* P = (const float4*)(batch + (size_t)t1 * D);
        const float4* N = (const float4*)(batch + (size_t)t2 * D);
        float sap = 0.0f, san = 0.0f;
        for (int idx = lane; idx < dq; idx += 64) {
            const float4 av = A[idx];
            const float4 pv = P[idx];
            const float4 nv = N[idx];
            float dx = av.x - pv.x, dy = av.y - pv.y, dz = av.z - pv.z, dw = av.w - pv.w;
            sap += dx * dx + dy * dy + dz * dz + dw * dw;
            dx = av.x - nv.x; dy = av.y - nv.y; dz = av.z - nv.z; dw = av.w - nv.w;
            san += dx * dx + dy * dy + dz * dz + dw * dw;
        }
        #pragma unroll
        for (int off = 1; off < 64; off <<= 1) {
            sap += __shfl_xor(sap, off, 64);
            san += __shfl_xor(san, off, 64);
        }
        if (lane == 0) {
            const float d_ap = sqrtf(sap + EPS_);
            const float d_an = sqrtf(san + EPS_);
            const float b    = beta[labels[t0]];
            const float pos  = fmaxf(d_ap - b + MARGIN, 0.0f);
            const float neg  = fmaxf(b - d_an + MARGIN, 0.0f);
            tot += pos + neg;
            cnt += ((pos > 0.0f) || (neg > 0.0f)) ? 1u : 0u;
        }
    }

    __shared__ float        s_tot[4];
    __shared__ unsigned int s_cnt[4];
    if (lane == 0) { s_tot[wid] = tot; s_cnt[wid] = cnt; }
    __syncthreads();
    if (threadIdx.x == 0) {
        float        bt = 0.0f;
        unsigned int bc = 0u;
        const int nw = blockDim.x >> 6;
        for (int i = 0; i < nw; ++i) { bt += s_tot[i]; bc += s_cnt[i]; }
        atomicAdd(ws_total, bt);
        atomicAdd(ws_cnt, bc);
    }
}

__global__ void finalize_kernel(const float* __restrict__ ws_total,
                                const unsigned int* __restrict__ ws_cnt,
                                float* __restrict__ out)
{
    const float total = ws_total[0];
    const float pc    = (float)ws_cnt[0];
    out[0] = (pc > 0.0f) ? (total / fmaxf(pc, 1.0f)) : total;
}

extern "C" void kernel_launch(void* const* d_in, const int* in_sizes, int n_in,
                              void* d_out, int out_size, void* d_ws, size_t ws_size,
                              hipStream_t stream)
{
    const float* batch    = (const float*)d_in[0];
    const float* beta     = (const float*)d_in[1];
    const int*   labels   = (const int*)d_in[2];
    const int*   triplets = (const int*)d_in[3];

    const int B = in_sizes[2];            // 4096
    const int D = in_sizes[0] / B;        // 512
    const int T = in_sizes[3] / 3;        // 65536

    float*        ws_total = (float*)d_ws;
    unsigned int* ws_cnt   = (unsigned int*)((char*)d_ws + sizeof(float));

    // zero accumulators every call (harness does not re-poison between replays)
    (void)hipMemsetAsync(d_ws, 0, 2 * sizeof(float), stream);

    // ws layout: [0,8) accumulators | [1024,+4B) beta_row | [32768,+4MiB) bf16 batch
    const size_t brow_off = 1024;
    const size_t hb_off   = 32768;
    const size_t need     = hb_off + (size_t)B * D * 2;
    const bool fast = (D == 512) && (ws_size >= need);

    if (fast) {
        float* beta_row = (float*)((char*)d_ws + brow_off);
        uint4* hb       = (uint4*)((char*)d_ws + hb_off);

        const int n8 = (B * D) / 8;
        to_bf16_kernel<<<(n8 + 255) / 256, 256, 0, stream>>>(batch, hb, n8);
        beta_row_kernel<<<(B + 255) / 256, 256, 0, stream>>>(beta, labels, beta_row, B);

        // 32 triplets per block (4 waves x 2 iters x 4 triplets)
        const int grid = (T + 31) / 32;
        triplet_loss_bf16_v2<<<grid, 256, 0, stream>>>(
            hb, beta_row, triplets, T, ws_total, ws_cnt);
    } else {
        const int block = 256;
        int grid = 2048;
        const int max_grid = (T + 3) / 4;
        if (grid > max_grid) grid = max_grid;
        triplet_loss_generic<<<grid, block, 0, stream>>>(
            batch, beta, labels, triplets, T, D, ws_total, ws_cnt);
    }

    finalize_kernel<<<1, 1, 0, stream>>>(ws_total, ws_cnt, (float*)d_out);
}

// Round 7
// 54.218 us; speedup vs baseline: 2.2717x; 1.4389x over previous
//
#include <hip/hip_runtime.h>

#define MARGIN 0.2f
#define EPS_    1e-8f
#define NBLK    768
#define WPB     4                    // waves per block
#define NWAVES  (NBLK * WPB)         // 3072 waves, 2 triplets each per tile-pass

// ---------------------------------------------------------------------------
// prep: fp32 -> bf16 (RNE) packed, beta_row[i] = beta[labels[i]], zero accs.
// ---------------------------------------------------------------------------
__device__ __forceinline__ unsigned pack_bf16(float lo, float hi)
{
    union { float f; unsigned u; } a, b;
    a.f = lo; b.f = hi;
    unsigned ua = (a.u + 0x7fffu + ((a.u >> 16) & 1u)) >> 16;
    unsigned ub = (b.u + 0x7fffu + ((b.u >> 16) & 1u)) & 0xffff0000u;
    return ua | ub;
}

__global__ __launch_bounds__(256) void prep_kernel(
    const float* __restrict__ in, uint4* __restrict__ out, int n8,
    const float* __restrict__ beta, const int* __restrict__ labels,
    float* __restrict__ beta_row, int B,
    float* __restrict__ ws_total, unsigned int* __restrict__ ws_cnt)
{
    int i = blockIdx.x * blockDim.x + threadIdx.x;
    if (i == 0) { *ws_total = 0.0f; *ws_cnt = 0u; }
    if (i < B) beta_row[i] = beta[labels[i]];
    if (i < n8) {
        const float4 a = ((const float4*)in)[2 * i + 0];
        const float4 b = ((const float4*)in)[2 * i + 1];
        uint4 r;
        r.x = pack_bf16(a.x, a.y);
        r.y = pack_bf16(a.z, a.w);
        r.z = pack_bf16(b.x, b.y);
        r.w = pack_bf16(b.z, b.w);
        out[i] = r;
    }
}

__device__ __forceinline__ void acc2(unsigned ua, unsigned uq, float& s)
{
    union { unsigned x; float f; } al, ah, ql, qh;
    al.x = ua << 16;        ah.x = ua & 0xffff0000u;
    ql.x = uq << 16;        qh.x = uq & 0xffff0000u;
    const float d0 = al.f - ql.f;
    const float d1 = ah.f - qh.f;
    s = fmaf(d0, d0, s);
    s = fmaf(d1, d1, s);
}

// ---------------------------------------------------------------------------
// Hot kernel v3: async global->LDS staging (cannot be register-sunk),
// per-wave private double-buffered slots, NO barriers, vmcnt(6)-counted
// single-tile-ahead pipeline.  D == 512, bf16 rows (1 KB = 64 uint4).
// Per wave per tile: 2 triplets x 3 rows = 6 global_load_lds (width 16:
// 64 lanes x 16 B = exactly one row per instruction).
// LDS: wave slot = 2 buf x 2 triplets x 3 KB = 12 KB; block = 48 KB.
// ---------------------------------------------------------------------------
__global__ __launch_bounds__(256) void triplet_loss_lds(
    const uint4* __restrict__ hb,
    const float* __restrict__ brow,
    const int*   __restrict__ trip,
    int T, int nit,
    float*        __restrict__ ws_total,
    unsigned int* __restrict__ ws_cnt)
{
    __shared__ char smem[WPB * 12 * 1024];
    const int lane = threadIdx.x & 63;
    const int wid  = threadIdx.x >> 6;
    const int l32  = lane & 31;
    const int half = lane >> 5;
    const int gw   = blockIdx.x * WPB + wid;
    char* const wbase  = &smem[wid * 12 * 1024];
    const int maxtile  = (T - 2) >> 1;      // T even (checked host-side)

    float        tot = 0.0f;
    unsigned int cnt = 0u;

    // stage tile `it` (2 triplets, 6 rows) into buffer parity it&1
    auto stage = [&](int it) {
        int tile = gw + it * NWAVES;
        if (tile > maxtile) tile = maxtile;
        const int2* p2 = (const int2*)(trip + 6 * tile);   // 24B-aligned
        const int2 w0 = p2[0], w1 = p2[1], w2 = p2[2];
        const int r0 = __builtin_amdgcn_readfirstlane(w0.x);
        const int r1 = __builtin_amdgcn_readfirstlane(w0.y);
        const int r2 = __builtin_amdgcn_readfirstlane(w1.x);
        const int r3 = __builtin_amdgcn_readfirstlane(w1.y);
        const int r4 = __builtin_amdgcn_readfirstlane(w2.x);
        const int r5 = __builtin_amdgcn_readfirstlane(w2.y);
        char* const d = wbase + (it & 1) * 6144;
        // 6 async stages; per-lane global src, lds dest base + lane*16
        __builtin_amdgcn_global_load_lds((const unsigned*)(hb + (size_t)r0 * 64 + lane),
                                         (unsigned*)(d + 0 * 1024 + lane * 16), 16, 0, 0);
        __builtin_amdgcn_global_load_lds((const unsigned*)(hb + (size_t)r1 * 64 + lane),
                                         (unsigned*)(d + 1 * 1024 + lane * 16), 16, 0, 0);
        __builtin_amdgcn_global_load_lds((const unsigned*)(hb + (size_t)r2 * 64 + lane),
                                         (unsigned*)(d + 2 * 1024 + lane * 16), 16, 0, 0);
        __builtin_amdgcn_global_load_lds((const unsigned*)(hb + (size_t)r3 * 64 + lane),
                                         (unsigned*)(d + 3 * 1024 + lane * 16), 16, 0, 0);
        __builtin_amdgcn_global_load_lds((const unsigned*)(hb + (size_t)r4 * 64 + lane),
                                         (unsigned*)(d + 4 * 1024 + lane * 16), 16, 0, 0);
        __builtin_amdgcn_global_load_lds((const unsigned*)(hb + (size_t)r5 * 64 + lane),
                                         (unsigned*)(d + 5 * 1024 + lane * 16), 16, 0, 0);
    };

    // consume one triplet from LDS slot (A at +0, P at +1K, N at +2K)
    auto process = [&](const char* slot, float b, bool valid) {
        const uint4* A = (const uint4*)(slot);
        const uint4* Q = (const uint4*)(slot + 1024 + (half << 10));
        const uint4 a0 = A[l32], a1 = A[l32 + 32];
        const uint4 q0 = Q[l32], q1 = Q[l32 + 32];
        float s = 0.0f;
        acc2(a0.x, q0.x, s); acc2(a0.y, q0.y, s);
        acc2(a0.z, q0.z, s); acc2(a0.w, q0.w, s);
        acc2(a1.x, q1.x, s); acc2(a1.y, q1.y, s);
        acc2(a1.z, q1.z, s); acc2(a1.w, q1.w, s);
        #pragma unroll
        for (int off = 1; off < 32; off <<= 1)
            s += __shfl_xor(s, off, 64);
        const float o = __shfl_xor(s, 32, 64);
        if (lane == 0 && valid) {
            const float d_ap = sqrtf(s + EPS_);   // lane0 is in the a-p half
            const float d_an = sqrtf(o + EPS_);
            const float pos  = fmaxf(d_ap - b + MARGIN, 0.0f);
            const float neg  = fmaxf(b - d_an + MARGIN, 0.0f);
            tot += pos + neg;
            cnt += ((pos > 0.0f) || (neg > 0.0f)) ? 1u : 0u;
        }
    };

    stage(0);
    for (int it = 0; it < nit; ++it) {
        stage(it + 1);                       // 6 newest vmem ops = next tile
        asm volatile("s_waitcnt vmcnt(6)" ::: "memory");   // tile `it` landed
        __builtin_amdgcn_sched_barrier(0);

        const int tile = gw + it * NWAVES;   // unclamped for validity
        const int tt   = tile > maxtile ? maxtile : tile;
        const int* p   = trip + 6 * tt;
        const float ba = brow[p[0]];
        const float bb = brow[p[3]];
        const char* s  = wbase + (it & 1) * 6144;
        process(s,        ba, (2 * tile)     < T);
        process(s + 3072, bb, (2 * tile + 1) < T);
    }

    __shared__ float        s_tot[WPB];
    __shared__ unsigned int s_cnt[WPB];
    if (lane == 0) { s_tot[wid] = tot; s_cnt[wid] = cnt; }
    __syncthreads();
    if (threadIdx.x == 0) {
        float        bt = 0.0f;
        unsigned int bc = 0u;
        #pragma unroll
        for (int i = 0; i < WPB; ++i) { bt += s_tot[i]; bc += s_cnt[i]; }
        atomicAdd(ws_total, bt);
        atomicAdd(ws_cnt, bc);
    }
}

// ---------------------------------------------------------------------------
// Standalone fp32 fallback (any D % 4 == 0; needs only 8 B of ws).
// ---------------------------------------------------------------------------
__global__ __launch_bounds__(256) void triplet_loss_generic(
    const float* __restrict__ batch,
    const float* __restrict__ beta,
    const int*   __restrict__ labels,
    const int*   __restrict__ triplets,
    int T, int D,
    float*        __restrict__ ws_total,
    unsigned int* __restrict__ ws_cnt)
{
    const int lane   = threadIdx.x & 63;
    const int wid    = threadIdx.x >> 6;
    const int gwave  = (blockIdx.x * blockDim.x + threadIdx.x) >> 6;
    const int nwaves = (gridDim.x * blockDim.x) >> 6;
    const int dq     = D >> 2;

    float        tot = 0.0f;
    unsigned int cnt = 0u;

    for (int t = gwave; t < T; t += nwaves) {
        const int t0 = triplets[3 * t + 0];
        const int t1 = triplets[3 * t + 1];
        const int t2 = triplets[3 * t + 2];
        const float4* A = (const float4*)(batch + (size_t)t0 * D);
        const float4* P = (const float4*)(batch + (size_t)t1 * D);
        const float4* N = (const float4*)(batch + (size_t)t2 * D);
        float sap = 0.0f, san = 0.0f;
        for (int idx = lane; idx < dq; idx += 64) {
            const float4 av = A[idx];
            const float4 pv = P[idx];
            const float4 nv = N[idx];
            float dx = av.x - pv.x, dy = av.y - pv.y, dz = av.z - pv.z, dw = av.w - pv.w;
            sap += dx * dx + dy * dy + dz * dz + dw * dw;
            dx = av.x - nv.x; dy = av.y - nv.y; dz = av.z - nv.z; dw = av.w - nv.w;
            san += dx * dx + dy * dy + dz * dz + dw * dw;
        }
        #pragma unroll
        for (int off = 1; off < 64; off <<= 1) {
            sap += __shfl_xor(sap, off, 64);
            san += __shfl_xor(san, off, 64);
        }
        if (lane == 0) {
            const float d_ap = sqrtf(sap + EPS_);
            const float d_an = sqrtf(san + EPS_);
            const float b    = beta[labels[t0]];
            const float pos  = fmaxf(d_ap - b + MARGIN, 0.0f);
            const float neg  = fmaxf(b - d_an + MARGIN, 0.0f);
            tot += pos + neg;
            cnt += ((pos > 0.0f) || (neg > 0.0f)) ? 1u : 0u;
        }
    }

    __shared__ float        s_tot[4];
    __shared__ unsigned int s_cnt[4];
    if (lane == 0) { s_tot[wid] = tot; s_cnt[wid] = cnt; }
    __syncthreads();
    if (threadIdx.x == 0) {
        float        bt = 0.0f;
        unsigned int bc = 0u;
        const int nw = blockDim.x >> 6;
        for (int i = 0; i < nw; ++i) { bt += s_tot[i]; bc += s_cnt[i]; }
        atomicAdd(ws_total, bt);
        atomicAdd(ws_cnt, bc);
    }
}

__global__ void finalize_kernel(const float* __restrict__ ws_total,
                                const unsigned int* __restrict__ ws_cnt,
                                float* __restrict__ out)
{
    const float total = ws_total[0];
    const float pc    = (float)ws_cnt[0];
    out[0] = (pc > 0.0f) ? (total / fmaxf(pc, 1.0f)) : total;
}

extern "C" void kernel_launch(void* const* d_in, const int* in_sizes, int n_in,
                              void* d_out, int out_size, void* d_ws, size_t ws_size,
                              hipStream_t stream)
{
    const float* batch    = (const float*)d_in[0];
    const float* beta     = (const float*)d_in[1];
    const int*   labels   = (const int*)d_in[2];
    const int*   triplets = (const int*)d_in[3];

    const int B = in_sizes[2];            // 4096
    const int D = in_sizes[0] / B;        // 512
    const int T = in_sizes[3] / 3;        // 65536

    float*        ws_total = (float*)d_ws;
    unsigned int* ws_cnt   = (unsigned int*)((char*)d_ws + sizeof(float));

    // ws layout: [0,8) accumulators | [1024,+4B) beta_row | [32768,+4MiB) bf16 batch
    const size_t brow_off = 1024;
    const size_t hb_off   = 32768;
    const size_t need     = hb_off + (size_t)B * D * 2;
    const bool fast = (D == 512) && (ws_size >= need) && (T >= 2) && ((T & 1) == 0);

    if (fast) {
        float* beta_row = (float*)((char*)d_ws + brow_off);
        uint4* hb       = (uint4*)((char*)d_ws + hb_off);

        const int n8   = (B * D) / 8;
        const int pgrd = (n8 > B ? n8 : B);
        prep_kernel<<<(pgrd + 255) / 256, 256, 0, stream>>>(
            batch, hb, n8, beta, labels, beta_row, B, ws_total, ws_cnt);

        const int nit = (T + NWAVES * 2 - 1) / (NWAVES * 2);
        triplet_loss_lds<<<NBLK, 256, 0, stream>>>(
            hb, beta_row, triplets, T, nit, ws_total, ws_cnt);
    } else {
        (void)hipMemsetAsync(d_ws, 0, 2 * sizeof(float), stream);
        const int block = 256;
        int grid = 2048;
        const int max_grid = (T + 3) / 4;
        if (grid > max_grid) grid = max_grid;
        triplet_loss_generic<<<grid, block, 0, stream>>>(
            batch, beta, labels, triplets, T, D, ws_total, ws_cnt);
    }

    finalize_kernel<<<1, 1, 0, stream>>>(ws_total, ws_cnt, (float*)d_out);
}

// Round 9
// 52.605 us; speedup vs baseline: 2.3413x; 1.0307x over previous
//
#include <hip/hip_runtime.h>

#define MARGIN 0.2f
#define EPS_    1e-8f
#define NBLK    768
#define WPB     4                    // waves per block
#define NWAVES  (NBLK * WPB)         // 3072 waves, 2 triplets each per tile
#define WSLOT   (13 * 1024)          // per-wave LDS: 12K rows + 512 idx + 512 beta

struct Idx6 { int2 w0, w1, w2; };

// ---------------------------------------------------------------------------
// prep: fp32 -> bf16 (RNE); beta_tri[t] = beta[labels[trip[3t]]]; zero accs.
// ---------------------------------------------------------------------------
__device__ __forceinline__ unsigned pack_bf16(float lo, float hi)
{
    union { float f; unsigned u; } a, b;
    a.f = lo; b.f = hi;
    unsigned ua = (a.u + 0x7fffu + ((a.u >> 16) & 1u)) >> 16;
    unsigned ub = (b.u + 0x7fffu + ((b.u >> 16) & 1u)) & 0xffff0000u;
    return ua | ub;
}

__global__ __launch_bounds__(256) void prep_kernel(
    const float* __restrict__ in, uint4* __restrict__ out, int n8,
    const float* __restrict__ beta, const int* __restrict__ labels,
    const int* __restrict__ trip, float* __restrict__ beta_tri, int T,
    float* __restrict__ ws_total, unsigned int* __restrict__ ws_cnt)
{
    int i = blockIdx.x * blockDim.x + threadIdx.x;
    if (i == 0) { *ws_total = 0.0f; *ws_cnt = 0u; }
    if (i < T) beta_tri[i] = beta[labels[trip[3 * i]]];
    if (i < n8) {
        const float4 a = ((const float4*)in)[2 * i + 0];
        const float4 b = ((const float4*)in)[2 * i + 1];
        uint4 r;
        r.x = pack_bf16(a.x, a.y);
        r.y = pack_bf16(a.z, a.w);
        r.z = pack_bf16(b.x, b.y);
        r.w = pack_bf16(b.z, b.w);
        out[i] = r;
    }
}

__device__ __forceinline__ void acc2(unsigned ua, unsigned uq, float& s)
{
    union { unsigned x; float f; } al, ah, ql, qh;
    al.x = ua << 16;        ah.x = ua & 0xffff0000u;
    ql.x = uq << 16;        qh.x = uq & 0xffff0000u;
    const float d0 = al.f - ql.f;
    const float d1 = ah.f - qh.f;
    s = fmaf(d0, d0, s);
    s = fmaf(d1, d1, s);
}

// ---------------------------------------------------------------------------
// Hot kernel v5. All prefetched data flows through LDS (global_load_lds has
// no destination register -> nothing the compiler can sink or clobber):
//  - prologue: whole-kernel index slab (2 x width-4 gll, one vmcnt(0))
//  - loop:     7 gll/iter (6 rows + 1 beta pair), one s_waitcnt vmcnt(7)
// Indices for the next tile are ds_read one iteration ahead (lgkm-tracked).
// No __syncthreads in the loop; per-wave private LDS slots.
// ---------------------------------------------------------------------------
__global__ __launch_bounds__(256) void triplet_loss_pipe2(
    const uint4* __restrict__ hb,
    const float* __restrict__ beta_tri,
    const int*   __restrict__ trip,
    int T, int nit,
    float*        __restrict__ ws_total,
    unsigned int* __restrict__ ws_cnt)
{
    __shared__ char smem[WPB * WSLOT];
    const int lane = threadIdx.x & 63;
    const int wid  = threadIdx.x >> 6;
    const int l32  = lane & 31;
    const int half = lane >> 5;
    const int gw   = blockIdx.x * WPB + wid;
    char* const wbase = &smem[wid * WSLOT];
    char* const rows  = wbase;                    // 12 KB: 2 bufs x 6 KB
    char* const islab = wbase + 12 * 1024;        // 512 B: index slab
    char* const bslab = wbase + 12 * 1024 + 512;  // 512 B: 2 beta slots x 256
    const int maxtile = (T - 2) >> 1;             // T even (host-checked)

    float        tot = 0.0f;
    unsigned int cnt = 0u;

    // ---- prologue A: whole-kernel index slab (words g: tile g/6, elem g%6) ----
    {
        const int g0 = lane, g1 = 64 + lane;
        const int i0 = g0 / 6, e0 = g0 - 6 * i0;
        const int i1 = g1 / 6, e1 = g1 - 6 * i1;
        int tA = gw + i0 * NWAVES; if (tA > maxtile) tA = maxtile;
        int tB = gw + i1 * NWAVES; if (tB > maxtile) tB = maxtile;
        __builtin_amdgcn_global_load_lds((const unsigned*)(trip + 6 * tA + e0),
                                         (unsigned*)(islab + lane * 4), 4, 0, 0);
        __builtin_amdgcn_global_load_lds((const unsigned*)(trip + 6 * tB + e1),
                                         (unsigned*)(islab + 256 + lane * 4), 4, 0, 0);
    }
    asm volatile("s_waitcnt vmcnt(0)" ::: "memory");
    __builtin_amdgcn_sched_barrier(0);

    auto rd_idx = [&](int j) {
        Idx6 ix;
        const int2* p = (const int2*)(islab + 24 * j);
        ix.w0 = p[0]; ix.w1 = p[1]; ix.w2 = p[2];
        return ix;
    };

    // stage one tile: 6 rows + 1 beta pair = 7 VMEM, all global_load_lds
    auto stage = [&](const Idx6& ix, int parity, int tclamped) {
        char* const d = rows + parity * 6144;
        const int r[6] = { ix.w0.x, ix.w0.y, ix.w1.x, ix.w1.y, ix.w2.x, ix.w2.y };
        #pragma unroll
        for (int j = 0; j < 6; ++j) {
            const int rr = __builtin_amdgcn_readfirstlane(r[j]);
            __builtin_amdgcn_global_load_lds(
                (const unsigned*)(hb + (size_t)rr * 64 + lane),
                (unsigned*)(d + j * 1024 + lane * 16), 16, 0, 0);
        }
        __builtin_amdgcn_global_load_lds(
            (const unsigned*)(beta_tri + 2 * tclamped + (lane & 1)),
            (unsigned*)(bslab + parity * 256 + lane * 4), 4, 0, 0);
    };

    auto proc_one = [&](const char* slot, float b, bool valid) {
        const uint4* A = (const uint4*)(slot);
        const uint4* Q = (const uint4*)(slot + 1024 + (half << 10));
        const uint4 a0 = A[l32], a1 = A[l32 + 32];
        const uint4 q0 = Q[l32], q1 = Q[l32 + 32];
        float s = 0.0f;
        acc2(a0.x, q0.x, s); acc2(a0.y, q0.y, s);
        acc2(a0.z, q0.z, s); acc2(a0.w, q0.w, s);
        acc2(a1.x, q1.x, s); acc2(a1.y, q1.y, s);
        acc2(a1.z, q1.z, s); acc2(a1.w, q1.w, s);
        #pragma unroll
        for (int off = 1; off < 32; off <<= 1)
            s += __shfl_xor(s, off, 64);
        const float o = __shfl_xor(s, 32, 64);
        if (lane == 0 && valid) {
            const float d_ap = sqrtf(s + EPS_);   // lane0 is in the a-p half
            const float d_an = sqrtf(o + EPS_);
            const float pos  = fmaxf(d_ap - b + MARGIN, 0.0f);
            const float neg  = fmaxf(b - d_an + MARGIN, 0.0f);
            tot += pos + neg;
            cnt += ((pos > 0.0f) || (neg > 0.0f)) ? 1u : 0u;
        }
    };

    // ---- prologue B: stage tile0, preload tile1 indices ----
    {
        int t0c = gw; if (t0c > maxtile) t0c = maxtile;
        Idx6 i0 = rd_idx(0);
        stage(i0, 0, t0c);
    }
    Idx6 icur = rd_idx(1);
    asm volatile("s_waitcnt vmcnt(0)" ::: "memory");
    __builtin_amdgcn_sched_barrier(0);

    // ---- main loop: 7 VMEM/iter, one vmcnt(7) fence ----
    for (int it = 0; it < nit; ++it) {
        Idx6 inx = rd_idx(it + 2);                    // indices tile it+2 (lgkm)
        int tn = gw + (it + 1) * NWAVES; if (tn > maxtile) tn = maxtile;
        stage(icur, (it + 1) & 1, tn);                // 7 VMEM: tile it+1

        asm volatile("s_waitcnt vmcnt(7)" ::: "memory");   // tile it resident
        __builtin_amdgcn_sched_barrier(0);

        const int tile = gw + it * NWAVES;            // unclamped for validity
        const char*  s  = rows + (it & 1) * 6144;
        const float* bs = (const float*)(bslab + (it & 1) * 256);
        proc_one(s,        bs[0], (2 * tile)     < T);
        proc_one(s + 3072, bs[1], (2 * tile + 1) < T);

        icur = inx;
    }

    __shared__ float        s_tot[WPB];
    __shared__ unsigned int s_cnt[WPB];
    if (lane == 0) { s_tot[wid] = tot; s_cnt[wid] = cnt; }
    __syncthreads();
    if (threadIdx.x == 0) {
        float        bt = 0.0f;
        unsigned int bc = 0u;
        #pragma unroll
        for (int i = 0; i < WPB; ++i) { bt += s_tot[i]; bc += s_cnt[i]; }
        atomicAdd(ws_total, bt);
        atomicAdd(ws_cnt, bc);
    }
}

// ---------------------------------------------------------------------------
// Standalone fp32 fallback (any D % 4 == 0; needs only 8 B of ws).
// ---------------------------------------------------------------------------
__global__ __launch_bounds__(256) void triplet_loss_generic(
    const float* __restrict__ batch,
    const float* __restrict__ beta,
    const int*   __restrict__ labels,
    const int*   __restrict__ triplets,
    int T, int D,
    float*        __restrict__ ws_total,
    unsigned int* __restrict__ ws_cnt)
{
    const int lane   = threadIdx.x & 63;
    const int wid    = threadIdx.x >> 6;
    const int gwave  = (blockIdx.x * blockDim.x + threadIdx.x) >> 6;
    const int nwaves = (gridDim.x * blockDim.x) >> 6;
    const int dq     = D >> 2;

    float        tot = 0.0f;
    unsigned int cnt = 0u;

    for (int t = gwave; t < T; t += nwaves) {
        const int t0 = triplets[3 * t + 0];
        const int t1 = triplets[3 * t + 1];
        const int t2 = triplets[3 * t + 2];
        const float4* A = (const float4*)(batch + (size_t)t0 * D);
        const float4* P = (const float4*)(batch + (size_t)t1 * D);
        const float4* N = (const float4*)(batch + (size_t)t2 * D);
        float sap = 0.0f, san = 0.0f;
        for (int idx = lane; idx < dq; idx += 64) {
            const float4 av = A[idx];
            const float4 pv = P[idx];
            const float4 nv = N[idx];
            float dx = av.x - pv.x, dy = av.y - pv.y, dz = av.z - pv.z, dw = av.w - pv.w;
            sap += dx * dx + dy * dy + dz * dz + dw * dw;
            dx = av.x - nv.x; dy = av.y - nv.y; dz = av.z - nv.z; dw = av.w - nv.w;
            san += dx * dx + dy * dy + dz * dz + dw * dw;
        }
        #pragma unroll
        for (int off = 1; off < 64; off <<= 1) {
            sap += __shfl_xor(sap, off, 64);
            san += __shfl_xor(san, off, 64);
        }
        if (lane == 0) {
            const float d_ap = sqrtf(sap + EPS_);
            const float d_an = sqrtf(san + EPS_);
            const float b    = beta[labels[t0]];
            const float pos  = fmaxf(d_ap - b + MARGIN, 0.0f);
            const float neg  = fmaxf(b - d_an + MARGIN, 0.0f);
            tot += pos + neg;
            cnt += ((pos > 0.0f) || (neg > 0.0f)) ? 1u : 0u;
        }
    }

    __shared__ float        s_tot[4];
    __shared__ unsigned int s_cnt[4];
    if (lane == 0) { s_tot[wid] = tot; s_cnt[wid] = cnt; }
    __syncthreads();
    if (threadIdx.x == 0) {
        float        bt = 0.0f;
        unsigned int bc = 0u;
        const int nw = blockDim.x >> 6;
        for (int i = 0; i < nw; ++i) { bt += s_tot[i]; bc += s_cnt[i]; }
        atomicAdd(ws_total, bt);
        atomicAdd(ws_cnt, bc);
    }
}

__global__ void finalize_kernel(const float* __restrict__ ws_total,
                                const unsigned int* __restrict__ ws_cnt,
                                float* __restrict__ out)
{
    const float total = ws_total[0];
    const float pc    = (float)ws_cnt[0];
    out[0] = (pc > 0.0f) ? (total / fmaxf(pc, 1.0f)) : total;
}

extern "C" void kernel_launch(void* const* d_in, const int* in_sizes, int n_in,
                              void* d_out, int out_size, void* d_ws, size_t ws_size,
                              hipStream_t stream)
{
    const float* batch    = (const float*)d_in[0];
    const float* beta     = (const float*)d_in[1];
    const int*   labels   = (const int*)d_in[2];
    const int*   triplets = (const int*)d_in[3];

    const int B = in_sizes[2];            // 4096
    const int D = in_sizes[0] / B;        // 512
    const int T = in_sizes[3] / 3;        // 65536

    float*        ws_total = (float*)d_ws;
    unsigned int* ws_cnt   = (unsigned int*)((char*)d_ws + sizeof(float));

    // ws layout: [0,8) accs | [32768,+4MiB) bf16 batch | then beta_tri (4*T)
    const size_t hb_off = 32768;
    const size_t bt_off = hb_off + (size_t)B * D * 2;
    const size_t need   = bt_off + (size_t)T * 4;

    const int nit = (T / 2 + NWAVES - 1) / NWAVES;   // tiles per wave
    const bool fast = (D == 512) && (ws_size >= need) &&
                      (T >= 2) && ((T & 1) == 0) && (nit >= 1) && (nit <= 19);

    if (fast) {
        uint4* hb       = (uint4*)((char*)d_ws + hb_off);
        float* beta_tri = (float*)((char*)d_ws + bt_off);

        const int n8   = (B * D) / 8;
        int pgrd = n8 > B ? n8 : B;
        if (T > pgrd) pgrd = T;
        prep_kernel<<<(pgrd + 255) / 256, 256, 0, stream>>>(
            batch, hb, n8, beta, labels, triplets, beta_tri, T, ws_total, ws_cnt);

        triplet_loss_pipe2<<<NBLK, 256, 0, stream>>>(
            hb, beta_tri, triplets, T, nit, ws_total, ws_cnt);
    } else {
        (void)hipMemsetAsync(d_ws, 0, 2 * sizeof(float), stream);
        const int block = 256;
        int grid = 2048;
        const int max_grid = (T + 3) / 4;
        if (grid > max_grid) grid = max_grid;
        triplet_loss_generic<<<grid, block, 0, stream>>>(
            batch, beta, labels, triplets, T, D, ws_total, ws_cnt);
    }

    finalize_kernel<<<1, 1, 0, stream>>>(ws_total, ws_cnt, (float*)d_out);
}

// Round 10
// 50.931 us; speedup vs baseline: 2.4183x; 1.0329x over previous
//
#include <hip/hip_runtime.h>

#define MARGIN 0.2f
#define EPS_    1e-8f
#define BM 128
#define BK 64

typedef __attribute__((ext_vector_type(8))) short short8;
typedef __attribute__((ext_vector_type(4))) float f32x4;

// ---------------------------------------------------------------------------
// prep: fp32 -> bf16 (RNE) packed; beta_tri[t] = beta[labels[trip[3t]]];
// zero the accumulators.
// ---------------------------------------------------------------------------
__device__ __forceinline__ unsigned pack_bf16(float lo, float hi)
{
    union { float f; unsigned u; } a, b;
    a.f = lo; b.f = hi;
    unsigned ua = (a.u + 0x7fffu + ((a.u >> 16) & 1u)) >> 16;
    unsigned ub = (b.u + 0x7fffu + ((b.u >> 16) & 1u)) & 0xffff0000u;
    return ua | ub;
}

__global__ __launch_bounds__(256) void prep_kernel(
    const float* __restrict__ in, uint4* __restrict__ out, int n8,
    const float* __restrict__ beta, const int* __restrict__ labels,
    const int* __restrict__ trip, float* __restrict__ beta_tri, int T,
    float* __restrict__ ws_total, unsigned int* __restrict__ ws_cnt)
{
    int i = blockIdx.x * blockDim.x + threadIdx.x;
    if (i == 0) { *ws_total = 0.0f; *ws_cnt = 0u; }
    if (i < T) beta_tri[i] = beta[labels[trip[3 * i]]];
    if (i < n8) {
        const float4 a = ((const float4*)in)[2 * i + 0];
        const float4 b = ((const float4*)in)[2 * i + 1];
        uint4 r;
        r.x = pack_bf16(a.x, a.y);
        r.y = pack_bf16(a.z, a.w);
        r.z = pack_bf16(b.x, b.y);
        r.w = pack_bf16(b.z, b.w);
        out[i] = r;
    }
}

// ---------------------------------------------------------------------------
// G = X . X^T  (bf16 inputs, fp32 out), upper-triangle blocks only.
// m97 structure: 128x128 tile, BK=64, 4 waves, 4x4 fragments of
// mfma_f32_16x16x32_bf16, global_load_lds width-16 staging.
// A-operand: lane holds A[l&15][(l>>4)*8 ..+8]; B-operand: B[(l>>4)*8..][l&15]
// (B^T storage -> same row-slice load as A).  C/D: col=l&15, row=(l>>4)*4+j.
// G symmetric => any transpose-class layout error is output-invariant.
// ---------------------------------------------------------------------------
__global__ __launch_bounds__(256) void gemm_xxt(
    const char* __restrict__ xb,     // bf16 X, row stride D*2 bytes
    float* __restrict__ G, int B, int D)
{
    const int bm = blockIdx.y, bn = blockIdx.x;
    if (bn < bm) return;                       // upper triangle only
    __shared__ char At[BM * BK * 2];           // 16 KB, row-major [128][64] bf16
    __shared__ char Bt[BM * BK * 2];
    const int tid  = threadIdx.x;
    const int lane = tid & 63;
    const int w    = tid >> 6;
    const int wr   = w >> 1, wc = w & 1;
    const int rowb = D * 2;                    // global row stride bytes

    f32x4 acc[4][4] = {};

    const int nk = D / BK;
    for (int kk = 0; kk < nk; ++kk) {
        // stage both tiles: wave w stages chunks 4w..4w+3 of A and of B.
        // chunk c = rows 8c..8c+7 (8 rows x 128 B = 1 KB, LDS-linear).
        #pragma unroll
        for (int c4 = 0; c4 < 4; ++c4) {
            const int c = w * 4 + c4;
            const size_t arow = (size_t)bm * BM + c * 8 + (lane >> 3);
            const size_t brow = (size_t)bn * BM + c * 8 + (lane >> 3);
            const char* asrc = xb + arow * rowb + kk * (BK * 2) + (lane & 7) * 16;
            const char* bsrc = xb + brow * rowb + kk * (BK * 2) + (lane & 7) * 16;
            __builtin_amdgcn_global_load_lds((const unsigned*)asrc,
                (unsigned*)(At + c * 1024 + lane * 16), 16, 0, 0);
            __builtin_amdgcn_global_load_lds((const unsigned*)bsrc,
                (unsigned*)(Bt + c * 1024 + lane * 16), 16, 0, 0);
        }
        asm volatile("s_waitcnt vmcnt(0)" ::: "memory");
        __syncthreads();

        #pragma unroll
        for (int ks = 0; ks < 2; ++ks) {
            const int kbyte = ks * 64 + (lane >> 4) * 16;  // 8 bf16 = 16 B
            short8 a[4], b[4];
            #pragma unroll
            for (int m = 0; m < 4; ++m) {
                const int row = wr * 64 + m * 16 + (lane & 15);
                a[m] = *(const short8*)(At + row * 128 + kbyte);
            }
            #pragma unroll
            for (int n = 0; n < 4; ++n) {
                const int row = wc * 64 + n * 16 + (lane & 15);
                b[n] = *(const short8*)(Bt + row * 128 + kbyte);
            }
            #pragma unroll
            for (int m = 0; m < 4; ++m)
                #pragma unroll
                for (int n = 0; n < 4; ++n)
                    acc[m][n] = __builtin_amdgcn_mfma_f32_16x16x32_bf16(
                        a[m], b[n], acc[m][n], 0, 0, 0);
        }
        __syncthreads();
    }

    #pragma unroll
    for (int m = 0; m < 4; ++m)
        #pragma unroll
        for (int n = 0; n < 4; ++n)
            #pragma unroll
            for (int j = 0; j < 4; ++j) {
                const int row = bm * BM + wr * 64 + m * 16 + (lane >> 4) * 4 + j;
                const int col = bn * BM + wc * 64 + n * 16 + (lane & 15);
                G[(size_t)row * B + col] = acc[m][n][j];
            }
}

// ---------------------------------------------------------------------------
// phase 2: one thread per triplet; distances from G; block-reduce + atomic.
// ---------------------------------------------------------------------------
__global__ __launch_bounds__(256) void tri_eval(
    const float* __restrict__ G,
    const float* __restrict__ beta_tri,
    const int*   __restrict__ trip,
    int B, int T,
    float*        __restrict__ ws_total,
    unsigned int* __restrict__ ws_cnt)
{
    const int i = blockIdx.x * blockDim.x + threadIdx.x;
    float pn = 0.0f;
    int   c  = 0;
    if (i < T) {
        const int t0 = trip[3 * i + 0];
        const int t1 = trip[3 * i + 1];
        const int t2 = trip[3 * i + 2];
        const int r1 = t0 < t1 ? t0 : t1, c1 = t0 < t1 ? t1 : t0;
        const int r2 = t0 < t2 ? t0 : t2, c2 = t0 < t2 ? t2 : t0;
        const float g01 = G[(size_t)r1 * B + c1];
        const float g02 = G[(size_t)r2 * B + c2];
        const float n0  = G[(size_t)t0 * B + t0];
        const float n1  = G[(size_t)t1 * B + t1];
        const float n2  = G[(size_t)t2 * B + t2];
        const float b   = beta_tri[i];
        const float dap = sqrtf(fmaxf(n0 + n1 - 2.0f * g01, 0.0f) + EPS_);
        const float dan = sqrtf(fmaxf(n0 + n2 - 2.0f * g02, 0.0f) + EPS_);
        const float pos = fmaxf(dap - b + MARGIN, 0.0f);
        const float neg = fmaxf(b - dan + MARGIN, 0.0f);
        pn = pos + neg;
        c  = ((pos > 0.0f) || (neg > 0.0f)) ? 1 : 0;
    }
    #pragma unroll
    for (int off = 1; off < 64; off <<= 1) {
        pn += __shfl_xor(pn, off, 64);
        c  += __shfl_xor(c,  off, 64);
    }
    __shared__ float s_tot[4];
    __shared__ int   s_cnt[4];
    const int wid = threadIdx.x >> 6;
    if ((threadIdx.x & 63) == 0) { s_tot[wid] = pn; s_cnt[wid] = c; }
    __syncthreads();
    if (threadIdx.x == 0) {
        atomicAdd(ws_total, s_tot[0] + s_tot[1] + s_tot[2] + s_tot[3]);
        atomicAdd(ws_cnt, (unsigned)(s_cnt[0] + s_cnt[1] + s_cnt[2] + s_cnt[3]));
    }
}

// ---------------------------------------------------------------------------
// Standalone fp32 fallback (any D % 4 == 0; needs only 8 B of ws).
// ---------------------------------------------------------------------------
__global__ __launch_bounds__(256) void triplet_loss_generic(
    const float* __restrict__ batch,
    const float* __restrict__ beta,
    const int*   __restrict__ labels,
    const int*   __restrict__ triplets,
    int T, int D,
    float*        __restrict__ ws_total,
    unsigned int* __restrict__ ws_cnt)
{
    const int lane   = threadIdx.x & 63;
    const int wid    = threadIdx.x >> 6;
    const int gwave  = (blockIdx.x * blockDim.x + threadIdx.x) >> 6;
    const int nwaves = (gridDim.x * blockDim.x) >> 6;
    const int dq     = D >> 2;

    float        tot = 0.0f;
    unsigned int cnt = 0u;

    for (int t = gwave; t < T; t += nwaves) {
        const int t0 = triplets[3 * t + 0];
        const int t1 = triplets[3 * t + 1];
        const int t2 = triplets[3 * t + 2];
        const float4* A = (const float4*)(batch + (size_t)t0 * D);
        const float4* P = (const float4*)(batch + (size_t)t1 * D);
        const float4* N = (const float4*)(batch + (size_t)t2 * D);
        float sap = 0.0f, san = 0.0f;
        for (int idx = lane; idx < dq; idx += 64) {
            const float4 av = A[idx];
            const float4 pv = P[idx];
            const float4 nv = N[idx];
            float dx = av.x - pv.x, dy = av.y - pv.y, dz = av.z - pv.z, dw = av.w - pv.w;
            sap += dx * dx + dy * dy + dz * dz + dw * dw;
            dx = av.x - nv.x; dy = av.y - nv.y; dz = av.z - nv.z; dw = av.w - nv.w;
            san += dx * dx + dy * dy + dz * dz + dw * dw;
        }
        #pragma unroll
        for (int off = 1; off < 64; off <<= 1) {
            sap += __shfl_xor(sap, off, 64);
            san += __shfl_xor(san, off, 64);
        }
        if (lane == 0) {
            const float d_ap = sqrtf(sap + EPS_);
            const float d_an = sqrtf(san + EPS_);
            const float b    = beta[labels[t0]];
            const float pos  = fmaxf(d_ap - b + MARGIN, 0.0f);
            const float neg  = fmaxf(b - d_an + MARGIN, 0.0f);
            tot += pos + neg;
            cnt += ((pos > 0.0f) || (neg > 0.0f)) ? 1u : 0u;
        }
    }

    __shared__ float        s_tot[4];
    __shared__ unsigned int s_cnt[4];
    if (lane == 0) { s_tot[wid] = tot; s_cnt[wid] = cnt; }
    __syncthreads();
    if (threadIdx.x == 0) {
        float        bt = 0.0f;
        unsigned int bc = 0u;
        const int nw = blockDim.x >> 6;
        for (int i = 0; i < nw; ++i) { bt += s_tot[i]; bc += s_cnt[i]; }
        atomicAdd(ws_total, bt);
        atomicAdd(ws_cnt, bc);
    }
}

__global__ void finalize_kernel(const float* __restrict__ ws_total,
                                const unsigned int* __restrict__ ws_cnt,
                                float* __restrict__ out)
{
    const float total = ws_total[0];
    const float pc    = (float)ws_cnt[0];
    out[0] = (pc > 0.0f) ? (total / fmaxf(pc, 1.0f)) : total;
}

extern "C" void kernel_launch(void* const* d_in, const int* in_sizes, int n_in,
                              void* d_out, int out_size, void* d_ws, size_t ws_size,
                              hipStream_t stream)
{
    const float* batch    = (const float*)d_in[0];
    const float* beta     = (const float*)d_in[1];
    const int*   labels   = (const int*)d_in[2];
    const int*   triplets = (const int*)d_in[3];

    const int B = in_sizes[2];            // 4096
    const int D = in_sizes[0] / B;        // 512
    const int T = in_sizes[3] / 3;        // 65536

    float*        ws_total = (float*)d_ws;
    unsigned int* ws_cnt   = (unsigned int*)((char*)d_ws + sizeof(float));

    // ws layout: [0,8) accs | X bf16 at 32768 | G fp32 | beta_tri
    const size_t hb_off = 32768;
    const size_t g_off  = (hb_off + (size_t)B * D * 2 + 255) & ~(size_t)255;
    const size_t bt_off = g_off + (size_t)B * B * 4;
    const size_t need   = bt_off + (size_t)T * 4;

    const bool fast = (B % BM == 0) && (D % BK == 0) && (ws_size >= need) && (T >= 1);

    if (fast) {
        uint4* hb       = (uint4*)((char*)d_ws + hb_off);
        float* G        = (float*)((char*)d_ws + g_off);
        float* beta_tri = (float*)((char*)d_ws + bt_off);

        const int n8 = (B * D) / 8;
        int pgrd = n8 > T ? n8 : T;
        prep_kernel<<<(pgrd + 255) / 256, 256, 0, stream>>>(
            batch, hb, n8, beta, labels, triplets, beta_tri, T, ws_total, ws_cnt);

        dim3 ggrid(B / BM, B / BM);
        gemm_xxt<<<ggrid, 256, 0, stream>>>((const char*)hb, G, B, D);

        tri_eval<<<(T + 255) / 256, 256, 0, stream>>>(
            G, beta_tri, triplets, B, T, ws_total, ws_cnt);
    } else {
        (void)hipMemsetAsync(d_ws, 0, 2 * sizeof(float), stream);
        const int block = 256;
        int grid = 2048;
        const int max_grid = (T + 3) / 4;
        if (grid > max_grid) grid = max_grid;
        triplet_loss_generic<<<grid, block, 0, stream>>>(
            batch, beta, labels, triplets, T, D, ws_total, ws_cnt);
    }

    finalize_kernel<<<1, 1, 0, stream>>>(ws_total, ws_cnt, (float*)d_out);
}

// Round 11
// 49.910 us; speedup vs baseline: 2.4678x; 1.0205x over previous
//
#include <hip/hip_runtime.h>

#define MARGIN 0.2f
#define EPS_    1e-8f
#define BM 128
#define BK 64

typedef __attribute__((ext_vector_type(8))) short short8;
typedef __attribute__((ext_vector_type(4))) float f32x4;

// ---------------------------------------------------------------------------
// prep: fp32 -> bf16 (RNE) packed; zero the accumulators.
// ---------------------------------------------------------------------------
__device__ __forceinline__ unsigned pack_bf16(float lo, float hi)
{
    union { float f; unsigned u; } a, b;
    a.f = lo; b.f = hi;
    unsigned ua = (a.u + 0x7fffu + ((a.u >> 16) & 1u)) >> 16;
    unsigned ub = (b.u + 0x7fffu + ((b.u >> 16) & 1u)) & 0xffff0000u;
    return ua | ub;
}

__global__ __launch_bounds__(256) void prep_kernel(
    const float* __restrict__ in, uint4* __restrict__ out, int n8,
    float* __restrict__ ws_total, unsigned int* __restrict__ ws_cnt)
{
    int i = blockIdx.x * blockDim.x + threadIdx.x;
    if (i == 0) { *ws_total = 0.0f; *ws_cnt = 0u; }
    if (i < n8) {
        const float4 a = ((const float4*)in)[2 * i + 0];
        const float4 b = ((const float4*)in)[2 * i + 1];
        uint4 r;
        r.x = pack_bf16(a.x, a.y);
        r.y = pack_bf16(a.z, a.w);
        r.z = pack_bf16(b.x, b.y);
        r.w = pack_bf16(b.z, b.w);
        out[i] = r;
    }
}

// ---------------------------------------------------------------------------
// G = X . X^T (bf16 in, fp32 out), upper-triangle blocks, LINEAR triangular
// grid (528 blocks at B=4096). 2-phase double-buffered pipeline:
//   stage(kk+1, p^1) ; s_waitcnt vmcnt(8) ; s_barrier ;
//   compute(p)       ; s_waitcnt lgkmcnt(0) ; s_barrier
// Counted vmcnt keeps next-tile loads in flight across the barrier (T3/T4);
// raw s_barrier avoids __syncthreads' full vmcnt(0) drain.
// No LDS swizzle: T2 is regime-gated null on 2-phase 128^2 (m228d/m230).
// G symmetric => transpose-class layout errors are output-invariant.
// ---------------------------------------------------------------------------
__global__ __launch_bounds__(256) void gemm_xxt(
    const char* __restrict__ xb,     // bf16 X, row stride D*2 bytes
    float* __restrict__ G, int B, int D, int NB)
{
    // decode linear block id -> (bm, bn), bn >= bm
    int lin = blockIdx.x, bm = 0, rowlen = NB;
    while (lin >= rowlen) { lin -= rowlen; ++bm; --rowlen; }
    const int bn = bm + lin;

    __shared__ char At[2][BM * BK * 2];        // 2 x 16 KB
    __shared__ char Bt[2][BM * BK * 2];
    const int tid  = threadIdx.x;
    const int lane = tid & 63;
    const int w    = tid >> 6;
    const int wr   = w >> 1, wc = w & 1;
    const int rowb = D * 2;

    f32x4 acc[4][4] = {};

    // stage tile kk into parity p: wave w stages chunks 4w..4w+3 of A and B.
    auto stage = [&](int kk, int p) {
        #pragma unroll
        for (int c4 = 0; c4 < 4; ++c4) {
            const int c = w * 4 + c4;
            const size_t arow = (size_t)bm * BM + c * 8 + (lane >> 3);
            const size_t brow = (size_t)bn * BM + c * 8 + (lane >> 3);
            const char* asrc = xb + arow * rowb + kk * (BK * 2) + (lane & 7) * 16;
            const char* bsrc = xb + brow * rowb + kk * (BK * 2) + (lane & 7) * 16;
            __builtin_amdgcn_global_load_lds((const unsigned*)asrc,
                (unsigned*)(At[p] + c * 1024 + lane * 16), 16, 0, 0);
            __builtin_amdgcn_global_load_lds((const unsigned*)bsrc,
                (unsigned*)(Bt[p] + c * 1024 + lane * 16), 16, 0, 0);
        }
    };

    const int nk = D / BK;
    stage(0, 0);
    for (int kk = 0; kk < nk; ++kk) {
        const int p = kk & 1;
        if (kk + 1 < nk) {
            stage(kk + 1, p ^ 1);                      // 8 VMEM in flight
            asm volatile("s_waitcnt vmcnt(8)" ::: "memory");   // tile kk drained
        } else {
            asm volatile("s_waitcnt vmcnt(0)" ::: "memory");
        }
        __builtin_amdgcn_s_barrier();
        __builtin_amdgcn_sched_barrier(0);

        #pragma unroll
        for (int ks = 0; ks < 2; ++ks) {
            const int kbyte = ks * 64 + (lane >> 4) * 16;
            short8 a[4], b[4];
            #pragma unroll
            for (int m = 0; m < 4; ++m) {
                const int row = wr * 64 + m * 16 + (lane & 15);
                a[m] = *(const short8*)(At[p] + row * 128 + kbyte);
            }
            #pragma unroll
            for (int n = 0; n < 4; ++n) {
                const int row = wc * 64 + n * 16 + (lane & 15);
                b[n] = *(const short8*)(Bt[p] + row * 128 + kbyte);
            }
            #pragma unroll
            for (int m = 0; m < 4; ++m)
                #pragma unroll
                for (int n = 0; n < 4; ++n)
                    acc[m][n] = __builtin_amdgcn_mfma_f32_16x16x32_bf16(
                        a[m], b[n], acc[m][n], 0, 0, 0);
        }
        asm volatile("s_waitcnt lgkmcnt(0)" ::: "memory");
        __builtin_amdgcn_sched_barrier(0);
        __builtin_amdgcn_s_barrier();
    }

    #pragma unroll
    for (int m = 0; m < 4; ++m)
        #pragma unroll
        for (int n = 0; n < 4; ++n)
            #pragma unroll
            for (int j = 0; j < 4; ++j) {
                const int row = bm * BM + wr * 64 + m * 16 + (lane >> 4) * 4 + j;
                const int col = bn * BM + wc * 64 + n * 16 + (lane & 15);
                G[(size_t)row * B + col] = acc[m][n][j];
            }
}

// ---------------------------------------------------------------------------
// phase 2: one thread per triplet; distances from G; beta fused (labels and
// beta are cache-hot: 16 KB + 400 B); block-reduce + one atomic pair.
// ---------------------------------------------------------------------------
__global__ __launch_bounds__(256) void tri_eval(
    const float* __restrict__ G,
    const float* __restrict__ beta,
    const int*   __restrict__ labels,
    const int*   __restrict__ trip,
    int B, int T,
    float*        __restrict__ ws_total,
    unsigned int* __restrict__ ws_cnt)
{
    const int i = blockIdx.x * blockDim.x + threadIdx.x;
    float pn = 0.0f;
    int   c  = 0;
    if (i < T) {
        const int t0 = trip[3 * i + 0];
        const int t1 = trip[3 * i + 1];
        const int t2 = trip[3 * i + 2];
        const int r1 = t0 < t1 ? t0 : t1, c1 = t0 < t1 ? t1 : t0;
        const int r2 = t0 < t2 ? t0 : t2, c2 = t0 < t2 ? t2 : t0;
        const float g01 = G[(size_t)r1 * B + c1];
        const float g02 = G[(size_t)r2 * B + c2];
        const float n0  = G[(size_t)t0 * B + t0];
        const float n1  = G[(size_t)t1 * B + t1];
        const float n2  = G[(size_t)t2 * B + t2];
        const float b   = beta[labels[t0]];
        const float dap = sqrtf(fmaxf(n0 + n1 - 2.0f * g01, 0.0f) + EPS_);
        const float dan = sqrtf(fmaxf(n0 + n2 - 2.0f * g02, 0.0f) + EPS_);
        const float pos = fmaxf(dap - b + MARGIN, 0.0f);
        const float neg = fmaxf(b - dan + MARGIN, 0.0f);
        pn = pos + neg;
        c  = ((pos > 0.0f) || (neg > 0.0f)) ? 1 : 0;
    }
    #pragma unroll
    for (int off = 1; off < 64; off <<= 1) {
        pn += __shfl_xor(pn, off, 64);
        c  += __shfl_xor(c,  off, 64);
    }
    __shared__ float s_tot[4];
    __shared__ int   s_cnt[4];
    const int wid = threadIdx.x >> 6;
    if ((threadIdx.x & 63) == 0) { s_tot[wid] = pn; s_cnt[wid] = c; }
    __syncthreads();
    if (threadIdx.x == 0) {
        atomicAdd(ws_total, s_tot[0] + s_tot[1] + s_tot[2] + s_tot[3]);
        atomicAdd(ws_cnt, (unsigned)(s_cnt[0] + s_cnt[1] + s_cnt[2] + s_cnt[3]));
    }
}

// ---------------------------------------------------------------------------
// Standalone fp32 fallback (any D % 4 == 0; needs only 8 B of ws).
// ---------------------------------------------------------------------------
__global__ __launch_bounds__(256) void triplet_loss_generic(
    const float* __restrict__ batch,
    const float* __restrict__ beta,
    const int*   __restrict__ labels,
    const int*   __restrict__ triplets,
    int T, int D,
    float*        __restrict__ ws_total,
    unsigned int* __restrict__ ws_cnt)
{
    const int lane   = threadIdx.x & 63;
    const int wid    = threadIdx.x >> 6;
    const int gwave  = (blockIdx.x * blockDim.x + threadIdx.x) >> 6;
    const int nwaves = (gridDim.x * blockDim.x) >> 6;
    const int dq     = D >> 2;

    float        tot = 0.0f;
    unsigned int cnt = 0u;

    for (int t = gwave; t < T; t += nwaves) {
        const int t0 = triplets[3 * t + 0];
        const int t1 = triplets[3 * t + 1];
        const int t2 = triplets[3 * t + 2];
        const float4* A = (const float4*)(batch + (size_t)t0 * D);
        const float4* P = (const float4*)(batch + (size_t)t1 * D);
        const float4* N = (const float4*)(batch + (size_t)t2 * D);
        float sap = 0.0f, san = 0.0f;
        for (int idx = lane; idx < dq; idx += 64) {
            const float4 av = A[idx];
            const float4 pv = P[idx];
            const float4 nv = N[idx];
            float dx = av.x - pv.x, dy = av.y - pv.y, dz = av.z - pv.z, dw = av.w - pv.w;
            sap += dx * dx + dy * dy + dz * dz + dw * dw;
            dx = av.x - nv.x; dy = av.y - nv.y; dz = av.z - nv.z; dw = av.w - nv.w;
            san += dx * dx + dy * dy + dz * dz + dw * dw;
        }
        #pragma unroll
        for (int off = 1; off < 64; off <<= 1) {
            sap += __shfl_xor(sap, off, 64);
            san += __shfl_xor(san, off, 64);
        }
        if (lane == 0) {
            const float d_ap = sqrtf(sap + EPS_);
            const float d_an = sqrtf(san + EPS_);
            const float b    = beta[labels[t0]];
            const float pos  = fmaxf(d_ap - b + MARGIN, 0.0f);
            const float neg  = fmaxf(b - d_an + MARGIN, 0.0f);
            tot += pos + neg;
            cnt += ((pos > 0.0f) || (neg > 0.0f)) ? 1u : 0u;
        }
    }

    __shared__ float        s_tot[4];
    __shared__ unsigned int s_cnt[4];
    if (lane == 0) { s_tot[wid] = tot; s_cnt[wid] = cnt; }
    __syncthreads();
    if (threadIdx.x == 0) {
        float        bt = 0.0f;
        unsigned int bc = 0u;
        const int nw = blockDim.x >> 6;
        for (int i = 0; i < nw; ++i) { bt += s_tot[i]; bc += s_cnt[i]; }
        atomicAdd(ws_total, bt);
        atomicAdd(ws_cnt, bc);
    }
}

__global__ void finalize_kernel(const float* __restrict__ ws_total,
                                const unsigned int* __restrict__ ws_cnt,
                                float* __restrict__ out)
{
    const float total = ws_total[0];
    const float pc    = (float)ws_cnt[0];
    out[0] = (pc > 0.0f) ? (total / fmaxf(pc, 1.0f)) : total;
}

extern "C" void kernel_launch(void* const* d_in, const int* in_sizes, int n_in,
                              void* d_out, int out_size, void* d_ws, size_t ws_size,
                              hipStream_t stream)
{
    const float* batch    = (const float*)d_in[0];
    const float* beta     = (const float*)d_in[1];
    const int*   labels   = (const int*)d_in[2];
    const int*   triplets = (const int*)d_in[3];

    const int B = in_sizes[2];            // 4096
    const int D = in_sizes[0] / B;        // 512
    const int T = in_sizes[3] / 3;        // 65536

    float*        ws_total = (float*)d_ws;
    unsigned int* ws_cnt   = (unsigned int*)((char*)d_ws + sizeof(float));

    // ws layout: [0,8) accs | X bf16 at 32768 | G fp32
    const size_t hb_off = 32768;
    const size_t g_off  = (hb_off + (size_t)B * D * 2 + 255) & ~(size_t)255;
    const size_t need   = g_off + (size_t)B * B * 4;

    const bool fast = (B % BM == 0) && (D % BK == 0) && (ws_size >= need) && (T >= 1);

    if (fast) {
        uint4* hb = (uint4*)((char*)d_ws + hb_off);
        float* G  = (float*)((char*)d_ws + g_off);

        const int n8 = (B * D) / 8;
        prep_kernel<<<(n8 + 255) / 256, 256, 0, stream>>>(
            batch, hb, n8, ws_total, ws_cnt);

        const int NB = B / BM;
        const int nblk = NB * (NB + 1) / 2;       // 528 upper-tri blocks
        gemm_xxt<<<nblk, 256, 0, stream>>>((const char*)hb, G, B, D, NB);

        tri_eval<<<(T + 255) / 256, 256, 0, stream>>>(
            G, beta, labels, triplets, B, T, ws_total, ws_cnt);
    } else {
        (void)hipMemsetAsync(d_ws, 0, 2 * sizeof(float), stream);
        const int block = 256;
        int grid = 2048;
        const int max_grid = (T + 3) / 4;
        if (grid > max_grid) grid = max_grid;
        triplet_loss_generic<<<grid, block, 0, stream>>>(
            batch, beta, labels, triplets, T, D, ws_total, ws_cnt);
    }

    finalize_kernel<<<1, 1, 0, stream>>>(ws_total, ws_cnt, (float*)d_out);
}